// Round 9
// baseline (418.268 us; speedup 1.0000x reference)
//
#include <hip/hip_runtime.h>
#include <hip/hip_bf16.h>
#include <math.h>

#define DIM 256          // D_IN == EMBED == 256
#define HEADS 8
#define HEAD_DIM 32

typedef short  s16x8 __attribute__((ext_vector_type(8)));
typedef float  f32x4 __attribute__((ext_vector_type(4)));

// fp32 -> bf16 (RNE) via bit ops
__device__ __forceinline__ unsigned short f2bf_rne(float f) {
  unsigned int b = __builtin_bit_cast(unsigned int, f);
  b = (b + 0x7FFFu + ((b >> 16) & 1u)) >> 16;
  return (unsigned short)b;
}
__device__ __forceinline__ float bf2f(unsigned short s) {
  unsigned int b = ((unsigned int)s) << 16;
  return __builtin_bit_cast(float, b);
}

// ---------------------------------------------------------------------------
// W transpose + split-bf16 convert, interleaved layout:
//   Wt[col][c(8)][kq(4)][hi x8 | lo x8]   (shorts; 512 shorts = 1KB per col)
// One (col,c) slice = 128 B contiguous -> full-cacheline B-fragment loads.
// ---------------------------------------------------------------------------
__global__ __launch_bounds__(256) void wtrans_kernel(
    const float* __restrict__ Wi, const float* __restrict__ Wj,
    short* __restrict__ Wt_i, short* __restrict__ Wt_j) {
  const int n = blockIdx.x & 255;
  const float* W = (blockIdx.x < 256) ? Wi : Wj;
  short* T = (blockIdx.x < 256) ? Wt_i : Wt_j;
  const int k = threadIdx.x;
  float f = W[k * 256 + n];
  unsigned short hb = f2bf_rne(f);
  unsigned short lb = f2bf_rne(f - bf2f(hb));
  const int c = k >> 5, r5 = k & 31, kq = r5 >> 3, j = r5 & 7;
  const int base = n * 512 + c * 64 + kq * 16;
  T[base + j] = (short)hb;
  T[base + 8 + j] = (short)lb;
}

// ---------------------------------------------------------------------------
// Split-bf16 MFMA dual projection, tile M=32 x N=256 x K=256 (full-K LDS).
// Block: 256 thr (4 waves); wave w owns cols w*64..w*64+63, all 32 rows.
// LDS: A hi + lo = 32 KiB. B-fragments register double-buffered: subchunk
// c+1's 8 loads issue before c's 24-MFMA train (explicit 1-deep pipeline).
// ---------------------------------------------------------------------------
__global__ __launch_bounds__(256, 4) void proj2_mfma_kernel(
    const float* __restrict__ nodes,
    const short* __restrict__ Wt_i, const short* __restrict__ Wt_j,
    const float* __restrict__ bi, const float* __restrict__ bj,
    float* __restrict__ Pi, float* __restrict__ Pj, int M) {
  __shared__ __align__(16) short Ah[32 * 256];  // 16 KiB
  __shared__ __align__(16) short Al[32 * 256];  // 16 KiB
  const int t = threadIdx.x;
  const int row0 = blockIdx.x * 32;

  // ---- stage A: 32 rows x 256 k, fp32 -> bf16 hi/lo, swizzled ----
  const float4* n4 = (const float4*)nodes;
  #pragma unroll
  for (int i = 0; i < 8; ++i) {
    int u = t + i * 256;            // 0..2047 float4 slots
    int r = u >> 6;                 // row 0..31
    int q = u & 63;                 // float4 within row
    int gr = row0 + r;
    float4 v = make_float4(0.f, 0.f, 0.f, 0.f);
    if (gr < M) v = n4[(size_t)gr * 64 + q];
    float fv[4] = {v.x, v.y, v.z, v.w};
    short hv[4], lv[4];
    #pragma unroll
    for (int j = 0; j < 4; ++j) {
      unsigned short hb = f2bf_rne(fv[j]);
      hv[j] = (short)hb;
      lv[j] = (short)f2bf_rne(fv[j] - bf2f(hb));
    }
    int boff = r * 512 + ((q * 8) ^ ((r & 7) << 4));  // 8B store, no straddle
    *(short4*)((char*)Ah + boff) = make_short4(hv[0], hv[1], hv[2], hv[3]);
    *(short4*)((char*)Al + boff) = make_short4(lv[0], lv[1], lv[2], lv[3]);
  }
  __syncthreads();

  const int lane = t & 63, cg = t >> 6;   // wave = col group (64 cols)
  const int l15 = lane & 15;
  const int kq = lane >> 4;               // 0..3

  #pragma unroll
  for (int pass = 0; pass < 2; ++pass) {
    const short* Wt = pass ? Wt_j : Wt_i;
    const float* bias = pass ? bj : bi;
    float* P = pass ? Pj : Pi;

    f32x4 acc[2][4];   // [mt][nt]
    #pragma unroll
    for (int mt = 0; mt < 2; ++mt)
      #pragma unroll
      for (int nt = 0; nt < 4; ++nt) acc[mt][nt] = (f32x4){0.f, 0.f, 0.f, 0.f};

    // B-fragment register double-buffer. Base per (nt): col*512 shorts.
    s16x8 Bh[2][4], Bl[2][4];
    #pragma unroll
    for (int nt = 0; nt < 4; ++nt) {
      const short* p = Wt + (cg * 64 + nt * 16 + l15) * 512 + kq * 16;  // c=0
      Bh[0][nt] = *(const s16x8*)p;
      Bl[0][nt] = *(const s16x8*)(p + 8);
    }

    #pragma unroll
    for (int c = 0; c < 8; ++c) {         // k-subchunk of 32
      const int cur = c & 1, nxt = cur ^ 1;
      // prefetch B for c+1 BEFORE this subchunk's MFMA train
      if (c + 1 < 8) {
        #pragma unroll
        for (int nt = 0; nt < 4; ++nt) {
          const short* p = Wt + (cg * 64 + nt * 16 + l15) * 512 +
                           (c + 1) * 64 + kq * 16;
          Bh[nxt][nt] = *(const s16x8*)p;
          Bl[nxt][nt] = *(const s16x8*)(p + 8);
        }
      }
      // A fragments for c
      s16x8 Ahf[2], Alf[2];
      #pragma unroll
      for (int mt = 0; mt < 2; ++mt) {
        int lr = mt * 16 + l15;
        int boff = lr * 512 + ((c * 64 + kq * 16) ^ ((lr & 7) << 4));
        Ahf[mt] = *(const s16x8*)((const char*)Ah + boff);
        Alf[mt] = *(const s16x8*)((const char*)Al + boff);
      }
      #pragma unroll
      for (int nt = 0; nt < 4; ++nt) {
        #pragma unroll
        for (int mt = 0; mt < 2; ++mt) {
          acc[mt][nt] = __builtin_amdgcn_mfma_f32_16x16x32_bf16(Ahf[mt], Bh[cur][nt], acc[mt][nt], 0, 0, 0);
          acc[mt][nt] = __builtin_amdgcn_mfma_f32_16x16x32_bf16(Alf[mt], Bh[cur][nt], acc[mt][nt], 0, 0, 0);
          acc[mt][nt] = __builtin_amdgcn_mfma_f32_16x16x32_bf16(Ahf[mt], Bl[cur][nt], acc[mt][nt], 0, 0, 0);
        }
      }
    }

    // epilogue: D frag (col = l15, row = kq*4 + j within 16-tile)
    #pragma unroll
    for (int nt = 0; nt < 4; ++nt) {
      int col = cg * 64 + nt * 16 + l15;
      float bv = bias[col];
      #pragma unroll
      for (int mt = 0; mt < 2; ++mt) {
        #pragma unroll
        for (int j = 0; j < 4; ++j) {
          int gr = row0 + mt * 16 + kq * 4 + j;
          if (gr < M) P[(size_t)gr * 256 + col] = acc[mt][nt][j] + bv;
        }
      }
    }
  }
}

// ---------------------------------------------------------------------------
// CSR build: histogram -> scan (A/B, bases folded downstream) -> scatter
// ---------------------------------------------------------------------------
__global__ void hist_kernel(const int* __restrict__ recv, int* __restrict__ cnt,
                            int E) {
  int e = blockIdx.x * 256 + threadIdx.x;
  if (e < E) atomicAdd(&cnt[recv[e]], 1);
}

__device__ __forceinline__ int block_scan256(int x, int t, int* wsum) {
  const int lane = t & 63, wid = t >> 6;
  #pragma unroll
  for (int d = 1; d < 64; d <<= 1) {
    int y = __shfl_up(x, (unsigned)d);
    if (lane >= d) x += y;
  }
  if (lane == 63) wsum[wid] = x;
  __syncthreads();
  int add = 0;
  if (wid > 0) add += wsum[0];
  if (wid > 1) add += wsum[1];
  if (wid > 2) add += wsum[2];
  x += add;
  __syncthreads();
  return x;
}

__global__ __launch_bounds__(256) void scanA_kernel(const int* __restrict__ cnt,
                                                    int* __restrict__ offs,
                                                    int* __restrict__ bsum,
                                                    int n) {
  __shared__ int wsum[4];
  const int t = threadIdx.x;
  const int i = blockIdx.x * 256 + t;
  int x = (i < n) ? cnt[i] : 0;
  int s = block_scan256(x, t, wsum);
  if (i < n) offs[i + 1] = s;
  if (t == 255) bsum[blockIdx.x] = s;
  if (t == 0 && blockIdx.x == 0) offs[0] = 0;
}

__global__ __launch_bounds__(256) void scanB_kernel(const int* __restrict__ bsum,
                                                    int* __restrict__ bbase,
                                                    int nb) {
  __shared__ int wsum[4];
  __shared__ int carry_s;
  const int t = threadIdx.x;
  if (t == 0) carry_s = 0;
  __syncthreads();
  for (int base = 0; base < nb; base += 256) {
    int i = base + t;
    int x = (i < nb) ? bsum[i] : 0;
    int s = block_scan256(x, t, wsum);
    int c = carry_s;
    if (i < nb) bbase[i] = c + s - x;
    __syncthreads();
    if (t == 255) carry_s = c + s;
    __syncthreads();
  }
}

// offs_final(m) = offs_p[m] + (m>0 ? bbase[(m-1)>>8] : 0)
__device__ __forceinline__ int final_off(const int* __restrict__ offs_p,
                                         const int* __restrict__ bbase, int m) {
  return offs_p[m] + (m > 0 ? bbase[(m - 1) >> 8] : 0);
}

__global__ void scatter_kernel(const int* __restrict__ recv,
                               const int* __restrict__ snd,
                               const int* __restrict__ offs_p,
                               const int* __restrict__ bbase,
                               int* __restrict__ cursor,
                               int* __restrict__ sorted_snd, int E) {
  int e = blockIdx.x * 256 + threadIdx.x;
  if (e < E) {
    int r = recv[e];
    int slot = final_off(offs_p, bbase, r) + atomicAdd(&cursor[r], 1);
    sorted_snd[slot] = snd[e];
  }
}

// ---------------------------------------------------------------------------
// Fused per-node kernel: one wave per receiver node (online softmax).
// Depth-3 prefetch on the Pi gather.
// ---------------------------------------------------------------------------
__device__ __forceinline__ float mish_f(float x) {
  float t = __expf(fminf(x, 40.f));
  float u = t * (t + 2.f);
  return x * u * __builtin_amdgcn_rcpf(u + 2.f);
}

__global__ __launch_bounds__(256) void node_kernel(
    const float* __restrict__ Pi, const float* __restrict__ Pj,
    const int* __restrict__ offs_p, const int* __restrict__ bbase,
    const int* __restrict__ sorted_snd,
    const float* __restrict__ a_w, const float* __restrict__ a_b,
    float* __restrict__ out, int n) {
  const int wid = threadIdx.x >> 6, lane = threadIdx.x & 63;
  const int r = blockIdx.x * 4 + wid;
  if (r >= n) return;

  const int beg = final_off(offs_p, bbase, r);
  const int end = final_off(offs_p, bbase, r + 1);
  const float4* Pi4 = (const float4*)Pi;
  const float4* Pj4 = (const float4*)Pj;

  const float4 pj = Pj4[r * 64 + lane];
  const float4 aw = ((const float4*)a_w)[lane & 7];
  const float ab = a_b[0];

  float4 acc = make_float4(0.f, 0.f, 0.f, 0.f);
  float m = -INFINITY, denom = 0.f;

  float4 p0 = make_float4(0.f, 0.f, 0.f, 0.f), p1 = p0, p2 = p0;
  if (beg < end)     p0 = Pi4[(size_t)sorted_snd[beg] * 64 + lane];
  if (beg + 1 < end) p1 = Pi4[(size_t)sorted_snd[beg + 1] * 64 + lane];
  if (beg + 2 < end) p2 = Pi4[(size_t)sorted_snd[beg + 2] * 64 + lane];

  for (int idx = beg; idx < end; ++idx) {
    float4 pi = p0;
    p0 = p1; p1 = p2;
    if (idx + 3 < end)
      p2 = Pi4[(size_t)sorted_snd[idx + 3] * 64 + lane];  // depth-3 prefetch

    float partial;
    partial  = mish_f(pi.x + pj.x) * aw.x;
    partial += mish_f(pi.y + pj.y) * aw.y;
    partial += mish_f(pi.z + pj.z) * aw.z;
    partial += mish_f(pi.w + pj.w) * aw.w;
    partial += __shfl_xor(partial, 1);
    partial += __shfl_xor(partial, 2);
    partial += __shfl_xor(partial, 4);

    float lo = partial + ab;
    float mn = fmaxf(m, lo);
    float scale = __expf(m - mn);
    float p = __expf(lo - mn);
    denom = denom * scale + p;
    acc.x = acc.x * scale + p * pi.x;
    acc.y = acc.y * scale + p * pi.y;
    acc.z = acc.z * scale + p * pi.z;
    acc.w = acc.w * scale + p * pi.w;
    m = mn;
  }

  float inv = (end > beg) ? 1.f / denom : 0.f;
  float4 o = make_float4(acc.x * inv, acc.y * inv, acc.z * inv, acc.w * inv);
  ((float4*)out)[r * 64 + lane] = o;
}

// ---------------------------------------------------------------------------
extern "C" void kernel_launch(void* const* d_in, const int* in_sizes, int n_in,
                              void* d_out, int out_size, void* d_ws,
                              size_t ws_size, hipStream_t stream) {
  const float* nodes = (const float*)d_in[0];
  const int* senders = (const int*)d_in[1];
  const int* receivers = (const int*)d_in[2];
  const float* Wi = (const float*)d_in[3];
  const float* bi = (const float*)d_in[4];
  const float* Wj = (const float*)d_in[5];
  const float* bj = (const float*)d_in[6];
  const float* a_w = (const float*)d_in[7];
  const float* a_b = (const float*)d_in[8];
  float* out = (float*)d_out;

  const int N = in_sizes[0] / DIM;
  const int E = in_sizes[1];
  const int nb = (N + 255) / 256;

  // workspace layout
  char* ws = (char*)d_ws;
  float* Pi = (float*)ws;                         // N*256 f32
  float* Pj = Pi + (size_t)N * DIM;               // N*256 f32
  int* cnt = (int*)(Pj + (size_t)N * DIM);        // N
  int* cursor = cnt + N;                          // N
  int* offs = cursor + N;                         // N+1
  int* bsum = offs + N + 1;                       // nb
  int* bbase = bsum + nb;                         // nb
  int* sorted_snd = bbase + nb;                   // E
  // Wt buffers alias sorted_snd: written/read strictly before scatter writes.
  // 2 x 256KB <= E*4B (1.6MB).
  short* Wt_i = (short*)(((uintptr_t)sorted_snd + 15) & ~(uintptr_t)15);
  short* Wt_j = Wt_i + 256 * 512;

  hipMemsetAsync(cnt, 0, (size_t)2 * N * sizeof(int), stream);

  wtrans_kernel<<<512, 256, 0, stream>>>(Wi, Wj, Wt_i, Wt_j);
  proj2_mfma_kernel<<<(N + 31) / 32, 256, 0, stream>>>(
      nodes, Wt_i, Wt_j, bi, bj, Pi, Pj, N);

  hist_kernel<<<(E + 255) / 256, 256, 0, stream>>>(receivers, cnt, E);
  scanA_kernel<<<nb, 256, 0, stream>>>(cnt, offs, bsum, N);
  scanB_kernel<<<1, 256, 0, stream>>>(bsum, bbase, nb);
  scatter_kernel<<<(E + 255) / 256, 256, 0, stream>>>(
      receivers, senders, offs, bbase, cursor, sorted_snd, E);

  node_kernel<<<(N + 3) / 4, 256, 0, stream>>>(Pi, Pj, offs, bbase, sorted_snd,
                                               a_w, a_b, out, N);
}

// Round 10
// 323.462 us; speedup vs baseline: 1.2931x; 1.2931x over previous
//
#include <hip/hip_runtime.h>
#include <hip/hip_bf16.h>
#include <math.h>

#define DIM 256          // D_IN == EMBED == 256
#define HEADS 8
#define HEAD_DIM 32

typedef short  s16x8 __attribute__((ext_vector_type(8)));
typedef float  f32x4 __attribute__((ext_vector_type(4)));

// fp32 -> bf16 (RNE) via bit ops
__device__ __forceinline__ unsigned short f2bf_rne(float f) {
  unsigned int b = __builtin_bit_cast(unsigned int, f);
  b = (b + 0x7FFFu + ((b >> 16) & 1u)) >> 16;
  return (unsigned short)b;
}
__device__ __forceinline__ float bf2f(unsigned short s) {
  unsigned int b = ((unsigned int)s) << 16;
  return __builtin_bit_cast(float, b);
}

// ---------------------------------------------------------------------------
// Fused: W transpose/split (blocks 0..511) + receiver histogram (blocks 512+).
// Wt layout: [col][c(8)][kq(4)][hi x8 | lo x8] shorts; (col,c) slice = 128 B.
// ---------------------------------------------------------------------------
__global__ __launch_bounds__(256) void wtrans_hist_kernel(
    const float* __restrict__ Wi, const float* __restrict__ Wj,
    short* __restrict__ Wt_i, short* __restrict__ Wt_j,
    const int* __restrict__ recv, int* __restrict__ cnt, int E) {
  const int b = blockIdx.x;
  if (b < 512) {
    const int n = b & 255;
    const float* W = (b < 256) ? Wi : Wj;
    short* T = (b < 256) ? Wt_i : Wt_j;
    const int k = threadIdx.x;
    float f = W[k * 256 + n];
    unsigned short hb = f2bf_rne(f);
    unsigned short lb = f2bf_rne(f - bf2f(hb));
    const int c = k >> 5, r5 = k & 31, kq = r5 >> 3, j = r5 & 7;
    const int base = n * 512 + c * 64 + kq * 16;
    T[base + j] = (short)hb;
    T[base + 8 + j] = (short)lb;
  } else {
    int e = (b - 512) * 256 + threadIdx.x;
    if (e < E) atomicAdd(&cnt[recv[e]], 1);
  }
}

// ---------------------------------------------------------------------------
// Split-bf16 MFMA dual projection, tile M=64 x N=256 x K=256 (full-K LDS).
// Block: 256 thr (4 waves); wave w owns cols w*64..w*64+63, all 64 rows.
// LDS: A hi + lo = 64 KiB -> 2 blocks/CU. B pipelined at (c,nt) granularity,
// depth-2, 3 rotating register slots (24 VGPR) -> no spill, ~24 MFMAs of
// lead time per B pair. 12 MFMAs per B hi/lo pair (4 mt x 3).
// ---------------------------------------------------------------------------
__global__ __launch_bounds__(256, 2) void proj2_mfma_kernel(
    const float* __restrict__ nodes,
    const short* __restrict__ Wt_i, const short* __restrict__ Wt_j,
    const float* __restrict__ bi, const float* __restrict__ bj,
    float* __restrict__ Pi, float* __restrict__ Pj, int M) {
  __shared__ __align__(16) short Ah[64 * 256];  // 32 KiB
  __shared__ __align__(16) short Al[64 * 256];  // 32 KiB
  const int t = threadIdx.x;
  const int row0 = blockIdx.x * 64;

  // ---- stage A: 64 rows x 256 k, fp32 -> bf16 hi/lo, swizzled ----
  const float4* n4 = (const float4*)nodes;
  #pragma unroll
  for (int i = 0; i < 16; ++i) {
    int u = t + i * 256;            // 0..4095 float4 slots
    int r = u >> 6;                 // row 0..63
    int q = u & 63;                 // float4 within row
    int gr = row0 + r;
    float4 v = make_float4(0.f, 0.f, 0.f, 0.f);
    if (gr < M) v = n4[(size_t)gr * 64 + q];
    float fv[4] = {v.x, v.y, v.z, v.w};
    short hv[4], lv[4];
    #pragma unroll
    for (int j = 0; j < 4; ++j) {
      unsigned short hb = f2bf_rne(fv[j]);
      hv[j] = (short)hb;
      lv[j] = (short)f2bf_rne(fv[j] - bf2f(hb));
    }
    int boff = r * 512 + ((q * 8) ^ ((r & 7) << 4));  // 8B store, no straddle
    *(short4*)((char*)Ah + boff) = make_short4(hv[0], hv[1], hv[2], hv[3]);
    *(short4*)((char*)Al + boff) = make_short4(lv[0], lv[1], lv[2], lv[3]);
  }
  __syncthreads();

  const int lane = t & 63, cg = t >> 6;   // wave = col group (64 cols)
  const int l15 = lane & 15;
  const int kq = lane >> 4;               // 0..3

  #pragma unroll
  for (int pass = 0; pass < 2; ++pass) {
    const short* Wt = pass ? Wt_j : Wt_i;
    const float* bias = pass ? bj : bi;
    float* P = pass ? Pj : Pi;

    f32x4 acc[4][4];   // [mt][nt]
    #pragma unroll
    for (int mt = 0; mt < 4; ++mt)
      #pragma unroll
      for (int nt = 0; nt < 4; ++nt) acc[mt][nt] = (f32x4){0.f, 0.f, 0.f, 0.f};

    // B pipeline: p = c*4+nt in [0,32), depth-2, slots p%3.
    s16x8 Bh[3], Bl[3];
    {
      const short* p0 = Wt + (cg * 64 + 0 * 16 + l15) * 512 + 0 * 64 + kq * 16;
      Bh[0] = *(const s16x8*)p0;  Bl[0] = *(const s16x8*)(p0 + 8);
      const short* p1 = Wt + (cg * 64 + 1 * 16 + l15) * 512 + 0 * 64 + kq * 16;
      Bh[1] = *(const s16x8*)p1;  Bl[1] = *(const s16x8*)(p1 + 8);
    }

    #pragma unroll
    for (int c = 0; c < 8; ++c) {         // k-subchunk of 32
      // A fragments for this subchunk (8 x ds_read_b128)
      s16x8 Ahf[4], Alf[4];
      #pragma unroll
      for (int mt = 0; mt < 4; ++mt) {
        int lr = mt * 16 + l15;
        int boff = lr * 512 + ((c * 64 + kq * 16) ^ ((lr & 7) << 4));
        Ahf[mt] = *(const s16x8*)((const char*)Ah + boff);
        Alf[mt] = *(const s16x8*)((const char*)Al + boff);
      }
      #pragma unroll
      for (int nt = 0; nt < 4; ++nt) {
        const int p = c * 4 + nt;
        const int pn = p + 2;
        if (pn < 32) {                    // prefetch for p+2
          const int cn = pn >> 2, ntn = pn & 3;
          const short* pp = Wt + (cg * 64 + ntn * 16 + l15) * 512 +
                            cn * 64 + kq * 16;
          Bh[pn % 3] = *(const s16x8*)pp;
          Bl[pn % 3] = *(const s16x8*)(pp + 8);
        }
        const s16x8 bh = Bh[p % 3], bl = Bl[p % 3];
        #pragma unroll
        for (int mt = 0; mt < 4; ++mt) {
          acc[mt][nt] = __builtin_amdgcn_mfma_f32_16x16x32_bf16(Ahf[mt], bh, acc[mt][nt], 0, 0, 0);
          acc[mt][nt] = __builtin_amdgcn_mfma_f32_16x16x32_bf16(Alf[mt], bh, acc[mt][nt], 0, 0, 0);
          acc[mt][nt] = __builtin_amdgcn_mfma_f32_16x16x32_bf16(Ahf[mt], bl, acc[mt][nt], 0, 0, 0);
        }
      }
    }

    // epilogue: D frag (col = l15, row = kq*4 + j within 16-tile)
    #pragma unroll
    for (int nt = 0; nt < 4; ++nt) {
      int col = cg * 64 + nt * 16 + l15;
      float bv = bias[col];
      #pragma unroll
      for (int mt = 0; mt < 4; ++mt) {
        #pragma unroll
        for (int j = 0; j < 4; ++j) {
          int gr = row0 + mt * 16 + kq * 4 + j;
          if (gr < M) P[(size_t)gr * 256 + col] = acc[mt][nt][j] + bv;
        }
      }
    }
  }
}

// ---------------------------------------------------------------------------
// CSR build: scan (A/B, bases folded downstream) -> scatter
// ---------------------------------------------------------------------------
__device__ __forceinline__ int block_scan256(int x, int t, int* wsum) {
  const int lane = t & 63, wid = t >> 6;
  #pragma unroll
  for (int d = 1; d < 64; d <<= 1) {
    int y = __shfl_up(x, (unsigned)d);
    if (lane >= d) x += y;
  }
  if (lane == 63) wsum[wid] = x;
  __syncthreads();
  int add = 0;
  if (wid > 0) add += wsum[0];
  if (wid > 1) add += wsum[1];
  if (wid > 2) add += wsum[2];
  x += add;
  __syncthreads();
  return x;
}

__global__ __launch_bounds__(256) void scanA_kernel(const int* __restrict__ cnt,
                                                    int* __restrict__ offs,
                                                    int* __restrict__ bsum,
                                                    int n) {
  __shared__ int wsum[4];
  const int t = threadIdx.x;
  const int i = blockIdx.x * 256 + t;
  int x = (i < n) ? cnt[i] : 0;
  int s = block_scan256(x, t, wsum);
  if (i < n) offs[i + 1] = s;
  if (t == 255) bsum[blockIdx.x] = s;
  if (t == 0 && blockIdx.x == 0) offs[0] = 0;
}

__global__ __launch_bounds__(256) void scanB_kernel(const int* __restrict__ bsum,
                                                    int* __restrict__ bbase,
                                                    int nb) {
  __shared__ int wsum[4];
  __shared__ int carry_s;
  const int t = threadIdx.x;
  if (t == 0) carry_s = 0;
  __syncthreads();
  for (int base = 0; base < nb; base += 256) {
    int i = base + t;
    int x = (i < nb) ? bsum[i] : 0;
    int s = block_scan256(x, t, wsum);
    int c = carry_s;
    if (i < nb) bbase[i] = c + s - x;
    __syncthreads();
    if (t == 255) carry_s = c + s;
    __syncthreads();
  }
}

// offs_final(m) = offs_p[m] + (m>0 ? bbase[(m-1)>>8] : 0)
__device__ __forceinline__ int final_off(const int* __restrict__ offs_p,
                                         const int* __restrict__ bbase, int m) {
  return offs_p[m] + (m > 0 ? bbase[(m - 1) >> 8] : 0);
}

__global__ void scatter_kernel(const int* __restrict__ recv,
                               const int* __restrict__ snd,
                               const int* __restrict__ offs_p,
                               const int* __restrict__ bbase,
                               int* __restrict__ cursor,
                               int* __restrict__ sorted_snd, int E) {
  int e = blockIdx.x * 256 + threadIdx.x;
  if (e < E) {
    int r = recv[e];
    int slot = final_off(offs_p, bbase, r) + atomicAdd(&cursor[r], 1);
    sorted_snd[slot] = snd[e];
  }
}

// ---------------------------------------------------------------------------
// Fused per-node kernel: one wave per receiver node (online softmax).
// Depth-3 prefetch on the Pi gather.
// ---------------------------------------------------------------------------
__device__ __forceinline__ float mish_f(float x) {
  float t = __expf(fminf(x, 40.f));
  float u = t * (t + 2.f);
  return x * u * __builtin_amdgcn_rcpf(u + 2.f);
}

__global__ __launch_bounds__(256) void node_kernel(
    const float* __restrict__ Pi, const float* __restrict__ Pj,
    const int* __restrict__ offs_p, const int* __restrict__ bbase,
    const int* __restrict__ sorted_snd,
    const float* __restrict__ a_w, const float* __restrict__ a_b,
    float* __restrict__ out, int n) {
  const int wid = threadIdx.x >> 6, lane = threadIdx.x & 63;
  const int r = blockIdx.x * 4 + wid;
  if (r >= n) return;

  const int beg = final_off(offs_p, bbase, r);
  const int end = final_off(offs_p, bbase, r + 1);
  const float4* Pi4 = (const float4*)Pi;
  const float4* Pj4 = (const float4*)Pj;

  const float4 pj = Pj4[r * 64 + lane];
  const float4 aw = ((const float4*)a_w)[lane & 7];
  const float ab = a_b[0];

  float4 acc = make_float4(0.f, 0.f, 0.f, 0.f);
  float m = -INFINITY, denom = 0.f;

  float4 p0 = make_float4(0.f, 0.f, 0.f, 0.f), p1 = p0, p2 = p0;
  if (beg < end)     p0 = Pi4[(size_t)sorted_snd[beg] * 64 + lane];
  if (beg + 1 < end) p1 = Pi4[(size_t)sorted_snd[beg + 1] * 64 + lane];
  if (beg + 2 < end) p2 = Pi4[(size_t)sorted_snd[beg + 2] * 64 + lane];

  for (int idx = beg; idx < end; ++idx) {
    float4 pi = p0;
    p0 = p1; p1 = p2;
    if (idx + 3 < end)
      p2 = Pi4[(size_t)sorted_snd[idx + 3] * 64 + lane];  // depth-3 prefetch

    float partial;
    partial  = mish_f(pi.x + pj.x) * aw.x;
    partial += mish_f(pi.y + pj.y) * aw.y;
    partial += mish_f(pi.z + pj.z) * aw.z;
    partial += mish_f(pi.w + pj.w) * aw.w;
    partial += __shfl_xor(partial, 1);
    partial += __shfl_xor(partial, 2);
    partial += __shfl_xor(partial, 4);

    float lo = partial + ab;
    float mn = fmaxf(m, lo);
    float scale = __expf(m - mn);
    float p = __expf(lo - mn);
    denom = denom * scale + p;
    acc.x = acc.x * scale + p * pi.x;
    acc.y = acc.y * scale + p * pi.y;
    acc.z = acc.z * scale + p * pi.z;
    acc.w = acc.w * scale + p * pi.w;
    m = mn;
  }

  float inv = (end > beg) ? 1.f / denom : 0.f;
  float4 o = make_float4(acc.x * inv, acc.y * inv, acc.z * inv, acc.w * inv);
  ((float4*)out)[r * 64 + lane] = o;
}

// ---------------------------------------------------------------------------
extern "C" void kernel_launch(void* const* d_in, const int* in_sizes, int n_in,
                              void* d_out, int out_size, void* d_ws,
                              size_t ws_size, hipStream_t stream) {
  const float* nodes = (const float*)d_in[0];
  const int* senders = (const int*)d_in[1];
  const int* receivers = (const int*)d_in[2];
  const float* Wi = (const float*)d_in[3];
  const float* bi = (const float*)d_in[4];
  const float* Wj = (const float*)d_in[5];
  const float* bj = (const float*)d_in[6];
  const float* a_w = (const float*)d_in[7];
  const float* a_b = (const float*)d_in[8];
  float* out = (float*)d_out;

  const int N = in_sizes[0] / DIM;
  const int E = in_sizes[1];
  const int nb = (N + 255) / 256;

  // workspace layout
  char* ws = (char*)d_ws;
  float* Pi = (float*)ws;                         // N*256 f32
  float* Pj = Pi + (size_t)N * DIM;               // N*256 f32
  int* cnt = (int*)(Pj + (size_t)N * DIM);        // N
  int* cursor = cnt + N;                          // N
  int* offs = cursor + N;                         // N+1
  int* bsum = offs + N + 1;                       // nb
  int* bbase = bsum + nb;                         // nb
  int* sorted_snd = bbase + nb;                   // E
  // Wt buffers alias sorted_snd: written/read strictly before scatter writes.
  // 2 x 256KB <= E*4B (1.6MB).
  short* Wt_i = (short*)(((uintptr_t)sorted_snd + 15) & ~(uintptr_t)15);
  short* Wt_j = Wt_i + 256 * 512;

  hipMemsetAsync(cnt, 0, (size_t)2 * N * sizeof(int), stream);

  const int histBlocks = (E + 255) / 256;
  wtrans_hist_kernel<<<512 + histBlocks, 256, 0, stream>>>(
      Wi, Wj, Wt_i, Wt_j, receivers, cnt, E);
  proj2_mfma_kernel<<<(N + 63) / 64, 256, 0, stream>>>(
      nodes, Wt_i, Wt_j, bi, bj, Pi, Pj, N);

  scanA_kernel<<<nb, 256, 0, stream>>>(cnt, offs, bsum, N);
  scanB_kernel<<<1, 256, 0, stream>>>(bsum, bbase, nb);
  scatter_kernel<<<histBlocks, 256, 0, stream>>>(
      receivers, senders, offs, bbase, cursor, sorted_snd, E);

  node_kernel<<<(N + 3) / 4, 256, 0, stream>>>(Pi, Pj, offs, bbase, sorted_snd,
                                               a_w, a_b, out, N);
}